// Round 18
// baseline (85.355 us; speedup 1.0000x reference)
//
#include <hip/hip_runtime.h>
#include <math.h>

#define HEADS 3
#define C_OUT 384
#define GAT_IN 24
#define HID 32
#define TSTEPS 12
#define NEG_SLOPE 0.2f
#define CAPW 64        // per-wave cached edges in k_aggx
#define SLOTS 96       // fixed slist stride per dst (P(deg>=96) ~ 1e-30)

typedef __attribute__((ext_vector_type(8))) short bf16x8;
typedef __attribute__((ext_vector_type(4))) float f32x4;

__device__ __forceinline__ float sigm(float x) {
  return 1.f / (1.f + __expf(-x));
}
__device__ __forceinline__ float tanh_fast(float x) {
  return 2.f / (1.f + __expf(-2.f * x)) - 1.f;
}
__device__ __forceinline__ unsigned short f2bf(float x) {
  unsigned int u = __float_as_uint(x);
  unsigned int r = u + 0x7fffu + ((u >> 16) & 1u);
  return (unsigned short)(r >> 16);
}
__device__ __forceinline__ float bf2f(unsigned short u) {
  return __uint_as_float((unsigned int)u << 16);
}
__device__ __forceinline__ float lrelu(float x) {
  return x >= 0.f ? x : NEG_SLOPE * x;
}

// ---------------- K_const: WWt/biasb fold + prep + cnt zero ----------------
__global__ __launch_bounds__(96) void k_const(const float* __restrict__ lin_w,
                                              const float* __restrict__ gat_bias,
                                              const float* __restrict__ wih,
                                              const float* __restrict__ bih,
                                              const float* __restrict__ att_src,
                                              const float* __restrict__ att_dst,
                                              unsigned short* __restrict__ WWt,
                                              float* __restrict__ biasb,
                                              float* __restrict__ vbuf,
                                              int* __restrict__ cnt, int N) {
  int b = blockIdx.x;
  if (b < 876) {  // fold
    int t = b / 73, k = b % 73;
    int g = threadIdx.x;  // 0..95
    __shared__ float s_w[32];
    if (g < 32) {
      if (k < 72) {
        int h = k / 24, j = k % 24;
        s_w[g] = lin_w[(size_t)(h * C_OUT + t * 32 + g) * GAT_IN + j] * (1.f / 3.f);
      } else {
        s_w[g] = gat_bias[t * 32 + g];
      }
    }
    __syncthreads();
    const float* wrow = wih + (size_t)g * 32;
    float acc = 0.f;
#pragma unroll
    for (int c = 0; c < 32; ++c) acc += s_w[c] * wrow[c];
    if (k < 72) {
      WWt[((size_t)t * 96 + g) * 96 + k] = f2bf(acc);
      if (k < 24) WWt[((size_t)t * 96 + g) * 96 + 72 + k] = 0;  // zero pad
    } else {
      biasb[t * 96 + g] = acc + bih[g];
    }
  } else if (b < 948) {  // prep (single wave)
    int bb = b - 876;  // 0..71
    int h = bb / 24, j = bb % 24;
    int lane = threadIdx.x;
    if (lane >= 64) return;
    float as = 0.f, ad = 0.f;
    for (int c = lane; c < C_OUT; c += 64) {
      float wv = lin_w[(size_t)(h * C_OUT + c) * GAT_IN + j];
      as += att_src[h * C_OUT + c] * wv;
      ad += att_dst[h * C_OUT + c] * wv;
    }
#pragma unroll
    for (int off = 32; off >= 1; off >>= 1) {
      as += __shfl_xor(as, off, 64);
      ad += __shfl_xor(ad, off, 64);
    }
    if (lane == 0) {
      vbuf[h * 24 + j] = as;
      vbuf[72 + h * 24 + j] = ad;
    }
  } else {  // zero cnt
    int i = (b - 948) * 96 + threadIdx.x;
    if (i < N) cnt[i] = 0;
  }
}

// ---------------- K_place: bucket edges by dst, fixed stride ---------------
__global__ void k_place(const int* __restrict__ esrc,
                        const int* __restrict__ edst, int* __restrict__ cnt,
                        int* __restrict__ slist, int E, int ET) {
  int e = blockIdx.x * blockDim.x + threadIdx.x;
  if (e >= ET) return;
  int d, s;
  if (e < E) { d = edst[e]; s = esrc[e]; }
  else { d = e - E; s = e - E; }
  int pos = atomicAdd(&cnt[d], 1);
  if (pos < SLOTS) slist[(size_t)d * SLOTS + pos] = s;
}

// ---------------- K6: logits + softmax + xf-space aggregation --------------
__global__ __launch_bounds__(256) void k_aggx(
    const float* __restrict__ xf, const float* __restrict__ vbuf,
    const int* __restrict__ slist, const int* __restrict__ cnt,
    unsigned short* __restrict__ Yb, int N) {
  __shared__ float s_v[144];
  __shared__ float s_w[4][CAPW][3];
  __shared__ unsigned short s_xb[4][CAPW][26];  // bf16 xf rows
  int tid = threadIdx.x, lane = tid & 63, wv = tid >> 6;
  if (tid < 144) s_v[tid] = vbuf[tid];
  __syncthreads();  // before any wave can exit
  int n = blockIdx.x * 4 + wv;
  if (n >= N) return;  // per-wave exit; no barriers below

  int deg = min(cnt[n], SLOTS);

  float xl = (lane < 24) ? xf[(size_t)n * 24 + lane] : 0.f;
  float ad0, ad1, ad2;
  {
    float p0 = (lane < 24) ? xl * s_v[72 + lane] : 0.f;
    float p1 = (lane < 24) ? xl * s_v[96 + lane] : 0.f;
    float p2 = (lane < 24) ? xl * s_v[120 + lane] : 0.f;
#pragma unroll
    for (int off = 32; off >= 1; off >>= 1) {
      p0 += __shfl_xor(p0, off, 64);
      p1 += __shfl_xor(p1, off, 64);
      p2 += __shfl_xor(p2, off, 64);
    }
    ad0 = p0; ad1 = p1; ad2 = p2;
  }

  float t0 = 0.f, t1 = 0.f, t2 = 0.f;
  for (int i = lane; i < deg; i += 64) {
    int s = slist[(size_t)n * SLOTS + i];
    const float4* xr = (const float4*)(xf + (size_t)s * 24);
    float xs[24];
#pragma unroll
    for (int q = 0; q < 6; ++q) {
      float4 v = xr[q];
      xs[4 * q] = v.x; xs[4 * q + 1] = v.y;
      xs[4 * q + 2] = v.z; xs[4 * q + 3] = v.w;
    }
    float as0 = 0.f, as1 = 0.f, as2 = 0.f;
#pragma unroll
    for (int j = 0; j < 24; ++j) {
      float v = xs[j];
      as0 += v * s_v[j];
      as1 += v * s_v[24 + j];
      as2 += v * s_v[48 + j];
    }
    float e0 = __expf(lrelu(as0 + ad0));
    float e1 = __expf(lrelu(as1 + ad1));
    float e2 = __expf(lrelu(as2 + ad2));
    if (i < CAPW) {
      s_w[wv][i][0] = e0; s_w[wv][i][1] = e1; s_w[wv][i][2] = e2;
#pragma unroll
      for (int j = 0; j < 24; ++j) s_xb[wv][i][j] = f2bf(xs[j]);
    }
    t0 += e0; t1 += e1; t2 += e2;
  }
#pragma unroll
  for (int off = 32; off >= 1; off >>= 1) {
    t0 += __shfl_xor(t0, off, 64);
    t1 += __shfl_xor(t1, off, 64);
    t2 += __shfl_xor(t2, off, 64);
  }
  float inv0 = 1.f / t0, inv1 = 1.f / t1, inv2 = 1.f / t2;

  int eg = lane >> 5;   // edge slot 0/1
  int c = lane & 31;    // channel (active c<24)
  float acc0 = 0.f, acc1 = 0.f, acc2 = 0.f;
  if (deg <= CAPW) {
    int cc = (c < 24) ? c : 0;
    float cmask = (c < 24) ? 1.f : 0.f;
#pragma unroll 2
    for (int i = eg; i < deg; i += 2) {
      float w0 = s_w[wv][i][0] * inv0;
      float w1 = s_w[wv][i][1] * inv1;
      float w2 = s_w[wv][i][2] * inv2;
      float xv = bf2f(s_xb[wv][i][cc]) * cmask;
      acc0 += w0 * xv; acc1 += w1 * xv; acc2 += w2 * xv;
    }
  } else {
    for (int i = eg; i < deg; i += 2) {
      int s = slist[(size_t)n * SLOTS + i];
      float as0 = 0.f, as1 = 0.f, as2 = 0.f;
      const float* xr = xf + (size_t)s * 24;
#pragma unroll
      for (int j = 0; j < 24; ++j) {
        float v = xr[j];
        as0 += v * s_v[j];
        as1 += v * s_v[24 + j];
        as2 += v * s_v[48 + j];
      }
      float w0 = __expf(lrelu(as0 + ad0)) * inv0;
      float w1 = __expf(lrelu(as1 + ad1)) * inv1;
      float w2 = __expf(lrelu(as2 + ad2)) * inv2;
      float xv = (c < 24) ? xf[(size_t)s * 24 + c] : 0.f;
      acc0 += w0 * xv; acc1 += w1 * xv; acc2 += w2 * xv;
    }
  }
  acc0 += __shfl_xor(acc0, 32, 64);
  acc1 += __shfl_xor(acc1, 32, 64);
  acc2 += __shfl_xor(acc2, 32, 64);
  if (lane < 24) {
    unsigned short* yr = Yb + (size_t)n * 72;
    yr[lane] = f2bf(acc0);
    yr[24 + lane] = f2bf(acc1);
    yr[48 + lane] = f2bf(acc2);
  }
}

// ---------------- K_rec2: MFMA-everything GRU, 16 nodes per 64-thr block ---
// Per step t: gi[t] = Y @ WWt[t] (18 MFMA, accumulators only — never stored)
// and gh = h @ whhT (6 MFMA, K=32). D layouts coincide (col=gate,row=node).
// Lane (hi=l>>4, c=l&15) holds gates for nodes hi*4+reg at k=c (tiles 0,2,4)
// and k=c+16 (tiles 1,3,5); h_prev stays in 8 f32 regs; next A-frag rebuilt
// via a 1 KB LDS tile. Replaces the per-lane 96-FMA serial loop that was
// instruction-bound at ~50 us (rounds 14-17).
__global__ __launch_bounds__(64) void k_rec2(
    const unsigned short* __restrict__ Yb,
    const unsigned short* __restrict__ WWt, const float* __restrict__ biasb,
    const float* __restrict__ whh, const float* __restrict__ bhh,
    const float* __restrict__ p1w, const float* __restrict__ p1b,
    const float* __restrict__ p2w, const float* __restrict__ p2b,
    float* __restrict__ out, int N) {
  __shared__ unsigned short h16[16][32];
  __shared__ float s_o[16][12];
  int l = threadIdx.x;
  int c = l & 15, hi = l >> 4;
  int m0 = blockIdx.x * 16;

  // Y A-frags: A[row=c][k=q*32+hi*8+j]; q=2 valid only for hi==0 (k 64..71)
  int row = min(m0 + c, N - 1);
  const unsigned short* yr = Yb + (size_t)row * 72;
  bf16x8 ya0 = *(const bf16x8*)(yr + hi * 8);
  bf16x8 ya1 = *(const bf16x8*)(yr + 32 + hi * 8);
  bf16x8 ya2 = {0, 0, 0, 0, 0, 0, 0, 0};
  if (hi == 0) ya2 = *(const bf16x8*)(yr + 64);

  // whhT B-frags: wb[nt][j] = whh[g=nt*16+c][k=hi*8+j]  (24 VGPRs, invariant)
  bf16x8 wb[6];
#pragma unroll
  for (int nt = 0; nt < 6; ++nt) {
    const float* wp = whh + (size_t)(nt * 16 + c) * 32 + hi * 8;
#pragma unroll
    for (int j = 0; j < 8; ++j) wb[nt][j] = (short)f2bf(wp[j]);
  }

  float bhr0 = bhh[c], bhr1 = bhh[c + 16];
  float bhz0 = bhh[32 + c], bhz1 = bhh[48 + c];
  float bhn0 = bhh[64 + c], bhn1 = bhh[80 + c];
  float p1c0 = p1w[c], p1c1 = p1w[c + 16], p1b0 = p1b[0];

  float hA[4] = {0.f, 0.f, 0.f, 0.f}, hB[4] = {0.f, 0.f, 0.f, 0.f};
  bf16x8 ha = {0, 0, 0, 0, 0, 0, 0, 0};

  for (int t = 0; t < TSTEPS; ++t) {
    const unsigned short* Wt = WWt + (size_t)t * 96 * 96;
    // gi = Y @ WWt[t] : 3 k-chunks x 6 tiles
    f32x4 g0 = {0,0,0,0}, g1 = {0,0,0,0}, g2 = {0,0,0,0};
    f32x4 g3 = {0,0,0,0}, g4 = {0,0,0,0}, g5 = {0,0,0,0};
#pragma unroll
    for (int q = 0; q < 3; ++q) {
      bf16x8 aq = (q == 0) ? ya0 : (q == 1) ? ya1 : ya2;
      int ko = q * 32 + hi * 8;
      bf16x8 b0 = *(const bf16x8*)(Wt + (size_t)(0 * 16 + c) * 96 + ko);
      bf16x8 b1 = *(const bf16x8*)(Wt + (size_t)(1 * 16 + c) * 96 + ko);
      bf16x8 b2 = *(const bf16x8*)(Wt + (size_t)(2 * 16 + c) * 96 + ko);
      bf16x8 b3 = *(const bf16x8*)(Wt + (size_t)(3 * 16 + c) * 96 + ko);
      bf16x8 b4 = *(const bf16x8*)(Wt + (size_t)(4 * 16 + c) * 96 + ko);
      bf16x8 b5 = *(const bf16x8*)(Wt + (size_t)(5 * 16 + c) * 96 + ko);
      g0 = __builtin_amdgcn_mfma_f32_16x16x32_bf16(aq, b0, g0, 0, 0, 0);
      g1 = __builtin_amdgcn_mfma_f32_16x16x32_bf16(aq, b1, g1, 0, 0, 0);
      g2 = __builtin_amdgcn_mfma_f32_16x16x32_bf16(aq, b2, g2, 0, 0, 0);
      g3 = __builtin_amdgcn_mfma_f32_16x16x32_bf16(aq, b3, g3, 0, 0, 0);
      g4 = __builtin_amdgcn_mfma_f32_16x16x32_bf16(aq, b4, g4, 0, 0, 0);
      g5 = __builtin_amdgcn_mfma_f32_16x16x32_bf16(aq, b5, g5, 0, 0, 0);
    }
    // gh = h @ whhT : 6 MFMA (K=32)
    f32x4 zz = {0,0,0,0};
    f32x4 h0 = __builtin_amdgcn_mfma_f32_16x16x32_bf16(ha, wb[0], zz, 0, 0, 0);
    f32x4 h1 = __builtin_amdgcn_mfma_f32_16x16x32_bf16(ha, wb[1], zz, 0, 0, 0);
    f32x4 h2 = __builtin_amdgcn_mfma_f32_16x16x32_bf16(ha, wb[2], zz, 0, 0, 0);
    f32x4 h3 = __builtin_amdgcn_mfma_f32_16x16x32_bf16(ha, wb[3], zz, 0, 0, 0);
    f32x4 h4 = __builtin_amdgcn_mfma_f32_16x16x32_bf16(ha, wb[4], zz, 0, 0, 0);
    f32x4 h5 = __builtin_amdgcn_mfma_f32_16x16x32_bf16(ha, wb[5], zz, 0, 0, 0);
    // gi bias (includes b_ih)
    const float* bt = biasb + t * 96;
    float br0 = bt[c], br1 = bt[16 + c];
    float bz0 = bt[32 + c], bz1 = bt[48 + c];
    float bn0 = bt[64 + c], bn1 = bt[80 + c];
    // gates + p1 projection
    float po[4];
#pragma unroll
    for (int reg = 0; reg < 4; ++reg) {
      float r0 = sigm(g0[reg] + br0 + h0[reg] + bhr0);
      float z0 = sigm(g2[reg] + bz0 + h2[reg] + bhz0);
      float n0 = tanh_fast(g4[reg] + bn0 + r0 * (h4[reg] + bhn0));
      hA[reg] = (1.f - z0) * n0 + z0 * hA[reg];
      float r1 = sigm(g1[reg] + br1 + h1[reg] + bhr1);
      float z1 = sigm(g3[reg] + bz1 + h3[reg] + bhz1);
      float n1 = tanh_fast(g5[reg] + bn1 + r1 * (h5[reg] + bhn1));
      hB[reg] = (1.f - z1) * n1 + z1 * hB[reg];
      h16[hi * 4 + reg][c] = f2bf(hA[reg]);
      h16[hi * 4 + reg][c + 16] = f2bf(hB[reg]);
      po[reg] = p1c0 * hA[reg] + p1c1 * hB[reg];
    }
#pragma unroll
    for (int off = 1; off < 16; off <<= 1) {
#pragma unroll
      for (int reg = 0; reg < 4; ++reg) po[reg] += __shfl_xor(po[reg], off, 64);
    }
    if (c == 0) {
#pragma unroll
      for (int reg = 0; reg < 4; ++reg) s_o[hi * 4 + reg][t] = po[reg] + p1b0;
    }
    __syncthreads();  // single wave: orders h16 writes before A-frag read
    ha = *(const bf16x8*)&h16[c][hi * 8];
  }
  __syncthreads();
  // p2 projection + store
  for (int idx = l; idx < 16 * TSTEPS; idx += 64) {
    int node = idx / TSTEPS, tt = idx % TSTEPS;
    int gn = m0 + node;
    if (gn < N) {
      float acc = p2b[tt];
#pragma unroll
      for (int s2 = 0; s2 < TSTEPS; ++s2)
        acc += p2w[tt * TSTEPS + s2] * s_o[node][s2];
      out[(size_t)gn * TSTEPS + tt] = acc;
    }
  }
}

// ---------------------------------------------------------------------------
extern "C" void kernel_launch(void* const* d_in, const int* in_sizes, int n_in,
                              void* d_out, int out_size, void* d_ws,
                              size_t ws_size, hipStream_t stream) {
  const float* x = (const float*)d_in[0];
  const int* ei = (const int*)d_in[1];
  const float* lin_w = (const float*)d_in[2];
  const float* att_src = (const float*)d_in[3];
  const float* att_dst = (const float*)d_in[4];
  const float* gat_bias = (const float*)d_in[5];
  const float* w_ih = (const float*)d_in[6];
  const float* w_hh = (const float*)d_in[7];
  const float* b_ih = (const float*)d_in[8];
  const float* b_hh = (const float*)d_in[9];
  const float* p1w = (const float*)d_in[10];
  const float* p1b = (const float*)d_in[11];
  const float* p2w = (const float*)d_in[12];
  const float* p2b = (const float*)d_in[13];

  int N = in_sizes[0] / GAT_IN;  // 10000
  int E = in_sizes[1] / 2;       // 160000
  int ET = E + N;

  size_t off = 0;
  char* base = (char*)d_ws;
  auto alloc = [&](size_t bytes) {
    void* p = base + off;
    off += (bytes + 255) & ~(size_t)255;
    return p;
  };
  unsigned short* Yb = (unsigned short*)alloc((size_t)N * 72 * 2);  // bf16 Y
  unsigned short* WWt = (unsigned short*)alloc((size_t)12 * 96 * 96 * 2);
  float* biasb = (float*)alloc((size_t)12 * 96 * 4);
  float* vbuf = (float*)alloc(144 * 4);
  int* cnt = (int*)alloc((size_t)N * 4);
  int* slist = (int*)alloc((size_t)N * SLOTS * 4);
  (void)ws_size; (void)n_in; (void)out_size;

  int zero_blocks = (N + 95) / 96;  // 105
  k_const<<<948 + zero_blocks, 96, 0, stream>>>(lin_w, gat_bias, w_ih, b_ih,
                                                att_src, att_dst, WWt, biasb,
                                                vbuf, cnt, N);
  k_place<<<(ET + 255) / 256, 256, 0, stream>>>(ei, ei + E, cnt, slist, E, ET);
  k_aggx<<<(N + 3) / 4, 256, 0, stream>>>(x, vbuf, slist, cnt, Yb, N);
  k_rec2<<<(N + 15) / 16, 64, 0, stream>>>(Yb, WWt, biasb, w_hh, b_hh, p1w,
                                           p1b, p2w, p2b, (float*)d_out, N);
}

// Round 19
// 79.255 us; speedup vs baseline: 1.0770x; 1.0770x over previous
//
#include <hip/hip_runtime.h>
#include <math.h>

#define HEADS 3
#define C_OUT 384
#define GAT_IN 24
#define HID 32
#define TSTEPS 12
#define NEG_SLOPE 0.2f
#define CAPW 64        // per-wave cached edges in k_aggx
#define SLOTS 96       // fixed slist stride per dst (P(deg>=96) ~ 1e-30)

typedef __attribute__((ext_vector_type(8))) short bf16x8;
typedef __attribute__((ext_vector_type(4))) float f32x4;

__device__ __forceinline__ float sigm(float x) {
  return 1.f / (1.f + __expf(-x));
}
__device__ __forceinline__ float tanh_fast(float x) {
  return 2.f / (1.f + __expf(-2.f * x)) - 1.f;
}
__device__ __forceinline__ unsigned short f2bf(float x) {
  unsigned int u = __float_as_uint(x);
  unsigned int r = u + 0x7fffu + ((u >> 16) & 1u);
  return (unsigned short)(r >> 16);
}
__device__ __forceinline__ unsigned int packbf(float lo, float hi) {
  return (unsigned int)f2bf(lo) | ((unsigned int)f2bf(hi) << 16);
}
__device__ __forceinline__ float bf_lo(unsigned int u) {
  return __uint_as_float(u << 16);
}
__device__ __forceinline__ float bf_hi(unsigned int u) {
  return __uint_as_float(u & 0xffff0000u);
}
__device__ __forceinline__ float bf2f(unsigned short u) {
  return __uint_as_float((unsigned int)u << 16);
}
__device__ __forceinline__ float lrelu(float x) {
  return x >= 0.f ? x : NEG_SLOPE * x;
}

// ---------------- K_const: WWf (fragment-major) + biasb + prep + cnt -------
// WWf[((t*3+q)*6+nt)*64 + l][j] (bf16) = B-frag element for MFMA tile
// (t, k-chunk q, col-tile nt), lane l=(hi*16+c): value WW[t][k=q*32+hi*8+j]
// [g=nt*16+c]; zero for k>=72. Coalesced 1KB wave-reads in k_rec2 phase A.
__global__ __launch_bounds__(96) void k_const(const float* __restrict__ lin_w,
                                              const float* __restrict__ gat_bias,
                                              const float* __restrict__ wih,
                                              const float* __restrict__ bih,
                                              const float* __restrict__ att_src,
                                              const float* __restrict__ att_dst,
                                              unsigned short* __restrict__ WWf,
                                              float* __restrict__ biasb,
                                              float* __restrict__ vbuf,
                                              int* __restrict__ cnt, int N) {
  int b = blockIdx.x;
  if (b < 876) {  // fold
    int t = b / 73, kk = b % 73;
    int g = threadIdx.x;  // 0..95
    __shared__ float s_w[32];
    if (g < 32) {
      if (kk < 72) {
        int h = kk / 24, j = kk % 24;
        s_w[g] = lin_w[(size_t)(h * C_OUT + t * 32 + g) * GAT_IN + j] * (1.f / 3.f);
      } else {
        s_w[g] = gat_bias[t * 32 + g];
      }
    }
    __syncthreads();
    const float* wrow = wih + (size_t)g * 32;
    float acc = 0.f;
#pragma unroll
    for (int c = 0; c < 32; ++c) acc += s_w[c] * wrow[c];
    int nt = g >> 4, c2 = g & 15;
    if (kk < 72) {
      int q = kk >> 5, rem = kk & 31, hi2 = rem >> 3, j2 = rem & 7;
      WWf[((((size_t)t * 3 + q) * 6 + nt) * 64 + hi2 * 16 + c2) * 8 + j2] =
          f2bf(acc);
      if (kk < 24) {  // zero-pad k 72..95 (q=2, hi>=1)
        int remz = kk + 8, hiz = remz >> 3, jz = remz & 7;
        WWf[((((size_t)t * 3 + 2) * 6 + nt) * 64 + hiz * 16 + c2) * 8 + jz] = 0;
      }
    } else {
      biasb[t * 96 + g] = acc + bih[g];
    }
  } else if (b < 948) {  // prep (single wave)
    int bb = b - 876;  // 0..71
    int h = bb / 24, j = bb % 24;
    int lane = threadIdx.x;
    if (lane >= 64) return;
    float as = 0.f, ad = 0.f;
    for (int c = lane; c < C_OUT; c += 64) {
      float wv = lin_w[(size_t)(h * C_OUT + c) * GAT_IN + j];
      as += att_src[h * C_OUT + c] * wv;
      ad += att_dst[h * C_OUT + c] * wv;
    }
#pragma unroll
    for (int off = 32; off >= 1; off >>= 1) {
      as += __shfl_xor(as, off, 64);
      ad += __shfl_xor(ad, off, 64);
    }
    if (lane == 0) {
      vbuf[h * 24 + j] = as;
      vbuf[72 + h * 24 + j] = ad;
    }
  } else {  // zero cnt
    int i = (b - 948) * 96 + threadIdx.x;
    if (i < N) cnt[i] = 0;
  }
}

// ---------------- K_place: bucket edges by dst, fixed stride ---------------
__global__ void k_place(const int* __restrict__ esrc,
                        const int* __restrict__ edst, int* __restrict__ cnt,
                        int* __restrict__ slist, int E, int ET) {
  int e = blockIdx.x * blockDim.x + threadIdx.x;
  if (e >= ET) return;
  int d, s;
  if (e < E) { d = edst[e]; s = esrc[e]; }
  else { d = e - E; s = e - E; }
  int pos = atomicAdd(&cnt[d], 1);
  if (pos < SLOTS) slist[(size_t)d * SLOTS + pos] = s;
}

// ---------------- K6: logits + softmax + xf-space aggregation --------------
__global__ __launch_bounds__(256) void k_aggx(
    const float* __restrict__ xf, const float* __restrict__ vbuf,
    const int* __restrict__ slist, const int* __restrict__ cnt,
    unsigned short* __restrict__ Yb, int N) {
  __shared__ float s_v[144];
  __shared__ float s_w[4][CAPW][3];
  __shared__ unsigned short s_xb[4][CAPW][26];  // bf16 xf rows
  int tid = threadIdx.x, lane = tid & 63, wv = tid >> 6;
  if (tid < 144) s_v[tid] = vbuf[tid];
  __syncthreads();  // before any wave can exit
  int n = blockIdx.x * 4 + wv;
  if (n >= N) return;  // per-wave exit; no barriers below

  int deg = min(cnt[n], SLOTS);

  float xl = (lane < 24) ? xf[(size_t)n * 24 + lane] : 0.f;
  float ad0, ad1, ad2;
  {
    float p0 = (lane < 24) ? xl * s_v[72 + lane] : 0.f;
    float p1 = (lane < 24) ? xl * s_v[96 + lane] : 0.f;
    float p2 = (lane < 24) ? xl * s_v[120 + lane] : 0.f;
#pragma unroll
    for (int off = 32; off >= 1; off >>= 1) {
      p0 += __shfl_xor(p0, off, 64);
      p1 += __shfl_xor(p1, off, 64);
      p2 += __shfl_xor(p2, off, 64);
    }
    ad0 = p0; ad1 = p1; ad2 = p2;
  }

  float t0 = 0.f, t1 = 0.f, t2 = 0.f;
  for (int i = lane; i < deg; i += 64) {
    int s = slist[(size_t)n * SLOTS + i];
    const float4* xr = (const float4*)(xf + (size_t)s * 24);
    float xs[24];
#pragma unroll
    for (int q = 0; q < 6; ++q) {
      float4 v = xr[q];
      xs[4 * q] = v.x; xs[4 * q + 1] = v.y;
      xs[4 * q + 2] = v.z; xs[4 * q + 3] = v.w;
    }
    float as0 = 0.f, as1 = 0.f, as2 = 0.f;
#pragma unroll
    for (int j = 0; j < 24; ++j) {
      float v = xs[j];
      as0 += v * s_v[j];
      as1 += v * s_v[24 + j];
      as2 += v * s_v[48 + j];
    }
    float e0 = __expf(lrelu(as0 + ad0));
    float e1 = __expf(lrelu(as1 + ad1));
    float e2 = __expf(lrelu(as2 + ad2));
    if (i < CAPW) {
      s_w[wv][i][0] = e0; s_w[wv][i][1] = e1; s_w[wv][i][2] = e2;
#pragma unroll
      for (int j = 0; j < 24; ++j) s_xb[wv][i][j] = f2bf(xs[j]);
    }
    t0 += e0; t1 += e1; t2 += e2;
  }
#pragma unroll
  for (int off = 32; off >= 1; off >>= 1) {
    t0 += __shfl_xor(t0, off, 64);
    t1 += __shfl_xor(t1, off, 64);
    t2 += __shfl_xor(t2, off, 64);
  }
  float inv0 = 1.f / t0, inv1 = 1.f / t1, inv2 = 1.f / t2;

  int eg = lane >> 5;   // edge slot 0/1
  int c = lane & 31;    // channel (active c<24)
  float acc0 = 0.f, acc1 = 0.f, acc2 = 0.f;
  if (deg <= CAPW) {
    int cc = (c < 24) ? c : 0;
    float cmask = (c < 24) ? 1.f : 0.f;
#pragma unroll 2
    for (int i = eg; i < deg; i += 2) {
      float w0 = s_w[wv][i][0] * inv0;
      float w1 = s_w[wv][i][1] * inv1;
      float w2 = s_w[wv][i][2] * inv2;
      float xv = bf2f(s_xb[wv][i][cc]) * cmask;
      acc0 += w0 * xv; acc1 += w1 * xv; acc2 += w2 * xv;
    }
  } else {
    for (int i = eg; i < deg; i += 2) {
      int s = slist[(size_t)n * SLOTS + i];
      float as0 = 0.f, as1 = 0.f, as2 = 0.f;
      const float* xr = xf + (size_t)s * 24;
#pragma unroll
      for (int j = 0; j < 24; ++j) {
        float v = xr[j];
        as0 += v * s_v[j];
        as1 += v * s_v[24 + j];
        as2 += v * s_v[48 + j];
      }
      float w0 = __expf(lrelu(as0 + ad0)) * inv0;
      float w1 = __expf(lrelu(as1 + ad1)) * inv1;
      float w2 = __expf(lrelu(as2 + ad2)) * inv2;
      float xv = (c < 24) ? xf[(size_t)s * 24 + c] : 0.f;
      acc0 += w0 * xv; acc1 += w1 * xv; acc2 += w2 * xv;
    }
  }
  acc0 += __shfl_xor(acc0, 32, 64);
  acc1 += __shfl_xor(acc1, 32, 64);
  acc2 += __shfl_xor(acc2, 32, 64);
  if (lane < 24) {
    unsigned short* yr = Yb + (size_t)n * 72;
    yr[lane] = f2bf(acc0);
    yr[24 + lane] = f2bf(acc1);
    yr[48 + lane] = f2bf(acc2);
  }
}

// ---------------- K_rec2: MFMA GRU, gi hoisted, 16 nodes / 64-thr block ----
// Phase A: gi[t] = Y @ WW[t] for all 12 t (216 independent MFMA, coalesced
// 1KB WWf frag loads) -> packed bf16 in lane-private LDS (producer==consumer
// lane: no transpose, no barrier). Phase B per step: 3 ds_read_b128 (gi) +
// 6 gh-MFMA + gates — replaces round-18's in-loop 24 uncoalesced global
// loads/step that left the chain ~10k cyc/step at 6% occupancy.
__global__ __launch_bounds__(64) void k_rec2(
    const unsigned short* __restrict__ Yb,
    const unsigned short* __restrict__ WWf, const float* __restrict__ biasb,
    const float* __restrict__ whh, const float* __restrict__ bhh,
    const float* __restrict__ p1w, const float* __restrict__ p1b,
    const float* __restrict__ p2w, const float* __restrict__ p2b,
    float* __restrict__ out, int N) {
  __shared__ unsigned int gi_s[12][64][12];  // [t][lane][2 uints x 6 tiles]
  __shared__ float s_bias[12][96];
  __shared__ unsigned short h16[16][32];
  __shared__ float s_o[16][12];
  int l = threadIdx.x;
  int c = l & 15, hi = l >> 4;
  int m0 = blockIdx.x * 16;

  for (int u = l; u < 12 * 96; u += 64) s_bias[u / 96][u % 96] = biasb[u];

  // Y A-frags: A[row=c][k=q*32+hi*8+j]; q=2 valid only for hi==0
  int row = min(m0 + c, N - 1);
  const unsigned short* yr = Yb + (size_t)row * 72;
  bf16x8 ya0 = *(const bf16x8*)(yr + hi * 8);
  bf16x8 ya1 = *(const bf16x8*)(yr + 32 + hi * 8);
  bf16x8 ya2 = {0, 0, 0, 0, 0, 0, 0, 0};
  if (hi == 0) ya2 = *(const bf16x8*)(yr + 64);

  // ---- phase A: gi for all t, stored packed to lane-private LDS ----
  for (int t = 0; t < TSTEPS; ++t) {
    f32x4 g0 = {0,0,0,0}, g1 = {0,0,0,0}, g2 = {0,0,0,0};
    f32x4 g3 = {0,0,0,0}, g4 = {0,0,0,0}, g5 = {0,0,0,0};
#pragma unroll
    for (int q = 0; q < 3; ++q) {
      bf16x8 aq = (q == 0) ? ya0 : (q == 1) ? ya1 : ya2;
      const unsigned short* bp =
          WWf + ((((size_t)t * 3 + q) * 6) * 64 + l) * 8;
      bf16x8 b0 = *(const bf16x8*)(bp + 0 * 512);
      bf16x8 b1 = *(const bf16x8*)(bp + 1 * 512);
      bf16x8 b2 = *(const bf16x8*)(bp + 2 * 512);
      bf16x8 b3 = *(const bf16x8*)(bp + 3 * 512);
      bf16x8 b4 = *(const bf16x8*)(bp + 4 * 512);
      bf16x8 b5 = *(const bf16x8*)(bp + 5 * 512);
      g0 = __builtin_amdgcn_mfma_f32_16x16x32_bf16(aq, b0, g0, 0, 0, 0);
      g1 = __builtin_amdgcn_mfma_f32_16x16x32_bf16(aq, b1, g1, 0, 0, 0);
      g2 = __builtin_amdgcn_mfma_f32_16x16x32_bf16(aq, b2, g2, 0, 0, 0);
      g3 = __builtin_amdgcn_mfma_f32_16x16x32_bf16(aq, b3, g3, 0, 0, 0);
      g4 = __builtin_amdgcn_mfma_f32_16x16x32_bf16(aq, b4, g4, 0, 0, 0);
      g5 = __builtin_amdgcn_mfma_f32_16x16x32_bf16(aq, b5, g5, 0, 0, 0);
    }
    unsigned int* gp = &gi_s[t][l][0];
    gp[0] = packbf(g0[0], g0[1]);  gp[1] = packbf(g0[2], g0[3]);
    gp[2] = packbf(g1[0], g1[1]);  gp[3] = packbf(g1[2], g1[3]);
    gp[4] = packbf(g2[0], g2[1]);  gp[5] = packbf(g2[2], g2[3]);
    gp[6] = packbf(g3[0], g3[1]);  gp[7] = packbf(g3[2], g3[3]);
    gp[8] = packbf(g4[0], g4[1]);  gp[9] = packbf(g4[2], g4[3]);
    gp[10] = packbf(g5[0], g5[1]); gp[11] = packbf(g5[2], g5[3]);
  }

  // whhT B-frags: wb[nt][j] = whh[g=nt*16+c][k=hi*8+j]  (24 VGPRs, invariant)
  bf16x8 wb[6];
#pragma unroll
  for (int nt = 0; nt < 6; ++nt) {
    const float* wp = whh + (size_t)(nt * 16 + c) * 32 + hi * 8;
#pragma unroll
    for (int j = 0; j < 8; ++j) wb[nt][j] = (short)f2bf(wp[j]);
  }

  float bhr0 = bhh[c], bhr1 = bhh[c + 16];
  float bhz0 = bhh[32 + c], bhz1 = bhh[48 + c];
  float bhn0 = bhh[64 + c], bhn1 = bhh[80 + c];
  float p1c0 = p1w[c], p1c1 = p1w[c + 16], p1b0 = p1b[0];

  float hA[4] = {0.f, 0.f, 0.f, 0.f}, hB[4] = {0.f, 0.f, 0.f, 0.f};
  bf16x8 ha = {0, 0, 0, 0, 0, 0, 0, 0};

  // ---- phase B: recurrence ----
  for (int t = 0; t < TSTEPS; ++t) {
    uint4 va = *(const uint4*)&gi_s[t][l][0];  // tiles 0,1
    uint4 vb = *(const uint4*)&gi_s[t][l][4];  // tiles 2,3
    uint4 vc = *(const uint4*)&gi_s[t][l][8];  // tiles 4,5
    f32x4 zz = {0, 0, 0, 0};
    f32x4 h0 = __builtin_amdgcn_mfma_f32_16x16x32_bf16(ha, wb[0], zz, 0, 0, 0);
    f32x4 h1 = __builtin_amdgcn_mfma_f32_16x16x32_bf16(ha, wb[1], zz, 0, 0, 0);
    f32x4 h2 = __builtin_amdgcn_mfma_f32_16x16x32_bf16(ha, wb[2], zz, 0, 0, 0);
    f32x4 h3 = __builtin_amdgcn_mfma_f32_16x16x32_bf16(ha, wb[3], zz, 0, 0, 0);
    f32x4 h4 = __builtin_amdgcn_mfma_f32_16x16x32_bf16(ha, wb[4], zz, 0, 0, 0);
    f32x4 h5 = __builtin_amdgcn_mfma_f32_16x16x32_bf16(ha, wb[5], zz, 0, 0, 0);
    const float* bt = &s_bias[t][0];
    float br0 = bt[c], br1 = bt[16 + c];
    float bz0 = bt[32 + c], bz1 = bt[48 + c];
    float bn0 = bt[64 + c], bn1 = bt[80 + c];
    float g0v[4] = {bf_lo(va.x), bf_hi(va.x), bf_lo(va.y), bf_hi(va.y)};
    float g1v[4] = {bf_lo(va.z), bf_hi(va.z), bf_lo(va.w), bf_hi(va.w)};
    float g2v[4] = {bf_lo(vb.x), bf_hi(vb.x), bf_lo(vb.y), bf_hi(vb.y)};
    float g3v[4] = {bf_lo(vb.z), bf_hi(vb.z), bf_lo(vb.w), bf_hi(vb.w)};
    float g4v[4] = {bf_lo(vc.x), bf_hi(vc.x), bf_lo(vc.y), bf_hi(vc.y)};
    float g5v[4] = {bf_lo(vc.z), bf_hi(vc.z), bf_lo(vc.w), bf_hi(vc.w)};
    float po[4];
#pragma unroll
    for (int reg = 0; reg < 4; ++reg) {
      float r0 = sigm(g0v[reg] + br0 + h0[reg] + bhr0);
      float z0 = sigm(g2v[reg] + bz0 + h2[reg] + bhz0);
      float n0 = tanh_fast(g4v[reg] + bn0 + r0 * (h4[reg] + bhn0));
      hA[reg] = (1.f - z0) * n0 + z0 * hA[reg];
      float r1 = sigm(g1v[reg] + br1 + h1[reg] + bhr1);
      float z1 = sigm(g3v[reg] + bz1 + h3[reg] + bhz1);
      float n1 = tanh_fast(g5v[reg] + bn1 + r1 * (h5[reg] + bhn1));
      hB[reg] = (1.f - z1) * n1 + z1 * hB[reg];
      h16[hi * 4 + reg][c] = f2bf(hA[reg]);
      h16[hi * 4 + reg][c + 16] = f2bf(hB[reg]);
      po[reg] = p1c0 * hA[reg] + p1c1 * hB[reg];
    }
#pragma unroll
    for (int off = 1; off < 16; off <<= 1) {
#pragma unroll
      for (int reg = 0; reg < 4; ++reg) po[reg] += __shfl_xor(po[reg], off, 64);
    }
    if (c == 0) {
#pragma unroll
      for (int reg = 0; reg < 4; ++reg) s_o[hi * 4 + reg][t] = po[reg] + p1b0;
    }
    __syncthreads();  // single wave: orders h16 writes before A-frag read
    ha = *(const bf16x8*)&h16[c][hi * 8];
  }
  __syncthreads();
  // p2 projection + store
  for (int idx = l; idx < 16 * TSTEPS; idx += 64) {
    int node = idx / TSTEPS, tt = idx % TSTEPS;
    int gn = m0 + node;
    if (gn < N) {
      float acc = p2b[tt];
#pragma unroll
      for (int s2 = 0; s2 < TSTEPS; ++s2)
        acc += p2w[tt * TSTEPS + s2] * s_o[node][s2];
      out[(size_t)gn * TSTEPS + tt] = acc;
    }
  }
}

// ---------------------------------------------------------------------------
extern "C" void kernel_launch(void* const* d_in, const int* in_sizes, int n_in,
                              void* d_out, int out_size, void* d_ws,
                              size_t ws_size, hipStream_t stream) {
  const float* x = (const float*)d_in[0];
  const int* ei = (const int*)d_in[1];
  const float* lin_w = (const float*)d_in[2];
  const float* att_src = (const float*)d_in[3];
  const float* att_dst = (const float*)d_in[4];
  const float* gat_bias = (const float*)d_in[5];
  const float* w_ih = (const float*)d_in[6];
  const float* w_hh = (const float*)d_in[7];
  const float* b_ih = (const float*)d_in[8];
  const float* b_hh = (const float*)d_in[9];
  const float* p1w = (const float*)d_in[10];
  const float* p1b = (const float*)d_in[11];
  const float* p2w = (const float*)d_in[12];
  const float* p2b = (const float*)d_in[13];

  int N = in_sizes[0] / GAT_IN;  // 10000
  int E = in_sizes[1] / 2;       // 160000
  int ET = E + N;

  size_t off = 0;
  char* base = (char*)d_ws;
  auto alloc = [&](size_t bytes) {
    void* p = base + off;
    off += (bytes + 255) & ~(size_t)255;
    return p;
  };
  unsigned short* Yb = (unsigned short*)alloc((size_t)N * 72 * 2);  // bf16 Y
  unsigned short* WWf = (unsigned short*)alloc((size_t)12 * 3 * 6 * 64 * 8 * 2);
  float* biasb = (float*)alloc((size_t)12 * 96 * 4);
  float* vbuf = (float*)alloc(144 * 4);
  int* cnt = (int*)alloc((size_t)N * 4);
  int* slist = (int*)alloc((size_t)N * SLOTS * 4);
  (void)ws_size; (void)n_in; (void)out_size;

  int zero_blocks = (N + 95) / 96;  // 105
  k_const<<<948 + zero_blocks, 96, 0, stream>>>(lin_w, gat_bias, w_ih, b_ih,
                                                att_src, att_dst, WWf, biasb,
                                                vbuf, cnt, N);
  k_place<<<(ET + 255) / 256, 256, 0, stream>>>(ei, ei + E, cnt, slist, E, ET);
  k_aggx<<<(N + 3) / 4, 256, 0, stream>>>(x, vbuf, slist, cnt, Yb, N);
  k_rec2<<<(N + 15) / 16, 64, 0, stream>>>(Yb, WWf, biasb, w_hh, b_hh, p1w,
                                           p1b, p2w, p2b, (float*)d_out, N);
}